// Round 1
// baseline (366.831 us; speedup 1.0000x reference)
//
#include <hip/hip_runtime.h>
#include <cstdint>

#define NBATCH 16
#define CCH    384
#define HW     64
#define PLANE  (HW*HW)

// ---------------- fused depthwise kernel ----------------
// one block (256 thr) per (n,c) 64x64 plane.
// stage 1: initial = 5x5 dwconv(x) + b0           (pad 2, zeros outside)
// stage 2: spatial = bsum + 21-tap combined horizontal + 21-tap combined vertical
//          (the 1x7/1x11/1x21 kernels share taps -> one 21-vector; same vertically)
#define XS_S  68    // x staging: 64 + 2*2 halo
#define IP_S  92    // initial staging row stride (92/4=23 f4, 23%8=7 -> full bank spread)
#define IP_R  84    // 64 + 2*10 rows
#define IP_C0 12    // col offset of w=0 (>=10 halo, f4-aligned)
#define IP_R0 10    // row offset of h=0

__global__ __launch_bounds__(256)
void dw_fused(const float* __restrict__ x,
              const float* __restrict__ w0, const float* __restrict__ b0,
              const float* __restrict__ w1, const float* __restrict__ b1,
              const float* __restrict__ w2, const float* __restrict__ b2,
              const float* __restrict__ w3, const float* __restrict__ b3,
              const float* __restrict__ w4, const float* __restrict__ b4,
              const float* __restrict__ w5, const float* __restrict__ b5,
              const float* __restrict__ w6, const float* __restrict__ b6,
              float* __restrict__ sp)
{
    __shared__ float xs[XS_S * XS_S];
    __shared__ float ip[IP_R * IP_S];
    __shared__ float sw0[25];
    __shared__ float swh[21];
    __shared__ float swv[21];
    __shared__ float sb[2];

    const int tid = threadIdx.x;
    const int c   = blockIdx.x % CCH;

    // ---- per-channel weights: 5x5 raw; 1-D kernels combined (all centered) ----
    if (tid < 25) {
        sw0[tid] = w0[c * 25 + tid];
    } else if (tid < 46) {                    // horizontal combined: w5(21) + w3(11) + w1(7)
        const int d = tid - 25, dj = d - 10;
        float v = w5[c * 21 + d];
        if (dj >= -5 && dj <= 5) v += w3[c * 11 + dj + 5];
        if (dj >= -3 && dj <= 3) v += w1[c * 7  + dj + 3];
        swh[d] = v;
    } else if (tid < 67) {                    // vertical combined: w6(21) + w4(11) + w2(7)
        const int d = tid - 46, di = d - 10;
        float v = w6[c * 21 + d];
        if (di >= -5 && di <= 5) v += w4[c * 11 + di + 5];
        if (di >= -3 && di <= 3) v += w2[c * 7  + di + 3];
        swv[d] = v;
    } else if (tid == 67) {
        sb[0] = b0[c];
    } else if (tid == 68) {
        sb[1] = b1[c] + b2[c] + b3[c] + b4[c] + b5[c] + b6[c];
    }

    // ---- zero 'initial' staging (halo must be exactly 0) ----
    {
        float4* p4 = reinterpret_cast<float4*>(ip);
        for (int i = tid; i < (IP_R * IP_S) / 4; i += 256)
            p4[i] = make_float4(0.f, 0.f, 0.f, 0.f);
    }
    // ---- stage x plane with +-2 zero halo ----
    {
        const float* xp = x + (size_t)blockIdx.x * PLANE;
        for (int i = tid; i < XS_S * XS_S; i += 256) {
            const int r = i / XS_S, cc = i - r * XS_S;
            const int gh = r - 2, gw = cc - 2;
            float v = 0.f;
            if ((unsigned)gh < (unsigned)HW && (unsigned)gw < (unsigned)HW)
                v = xp[gh * HW + gw];
            xs[i] = v;
        }
    }
    __syncthreads();

    // thread -> one 1x16 row segment: h in [0,64), ws in {0,16,32,48}
    const int h  = tid >> 2;
    const int ws = (tid & 3) << 4;

    float acc[16];
    // ---- stage 1: initial = 5x5 ----
    {
        const float bv = sb[0];
        #pragma unroll
        for (int p = 0; p < 16; ++p) acc[p] = bv;
    }
    #pragma unroll
    for (int i = 0; i < 5; ++i) {
        float f[20];
        const float* row = &xs[(h + i) * XS_S + ws];
        #pragma unroll
        for (int q = 0; q < 5; ++q) {
            const float4 v = *reinterpret_cast<const float4*>(row + 4 * q);
            f[4*q+0] = v.x; f[4*q+1] = v.y; f[4*q+2] = v.z; f[4*q+3] = v.w;
        }
        #pragma unroll
        for (int j = 0; j < 5; ++j) {
            const float wg = sw0[i * 5 + j];
            #pragma unroll
            for (int p = 0; p < 16; ++p) acc[p] += f[p + j] * wg;
        }
    }
    {
        float* dst = &ip[(h + IP_R0) * IP_S + IP_C0 + ws];
        #pragma unroll
        for (int q = 0; q < 4; ++q)
            *reinterpret_cast<float4*>(dst + 4 * q) =
                make_float4(acc[4*q], acc[4*q+1], acc[4*q+2], acc[4*q+3]);
    }
    __syncthreads();

    // ---- stage 2: spatial = bsum + horiz21 + vert21 ----
    {
        const float bv = sb[1];
        #pragma unroll
        for (int p = 0; p < 16; ++p) acc[p] = bv;
    }
    // horizontal: taps at ip col = IP_C0 + w + dj = ws + (2 + p + j), aligned window [ws, ws+40)
    {
        float f[40];
        const float* row = &ip[(h + IP_R0) * IP_S + ws];
        #pragma unroll
        for (int q = 0; q < 10; ++q) {
            const float4 v = *reinterpret_cast<const float4*>(row + 4 * q);
            f[4*q+0] = v.x; f[4*q+1] = v.y; f[4*q+2] = v.z; f[4*q+3] = v.w;
        }
        #pragma unroll
        for (int j = 0; j < 21; ++j) {
            const float wg = swh[j];
            #pragma unroll
            for (int p = 0; p < 16; ++p) acc[p] += f[2 + p + j] * wg;
        }
    }
    // vertical: rows h .. h+20 (== h + di + IP_R0, di=-10..10)
    #pragma unroll
    for (int i = 0; i < 21; ++i) {
        const float wg = swv[i];
        const float* row = &ip[(h + i) * IP_S + IP_C0 + ws];
        #pragma unroll
        for (int q = 0; q < 4; ++q) {
            const float4 v = *reinterpret_cast<const float4*>(row + 4 * q);
            acc[4*q+0] += v.x * wg; acc[4*q+1] += v.y * wg;
            acc[4*q+2] += v.z * wg; acc[4*q+3] += v.w * wg;
        }
    }
    // ---- store spatial ----
    {
        float* op = sp + (size_t)blockIdx.x * PLANE + h * HW + ws;
        #pragma unroll
        for (int q = 0; q < 4; ++q)
            *reinterpret_cast<float4*>(op + 4 * q) =
                make_float4(acc[4*q], acc[4*q+1], acc[4*q+2], acc[4*q+3]);
    }
}

// ---------------- 1x1 pointwise conv as fp32 GEMM ----------------
// out[n] (384 x 4096) = wa (384 x 384) @ sp[n] (384 x 4096) + ba
// block: 64(co) x 256(px) tile, 256 threads, 8x8 per thread, K-tile 16
#define KT   16
#define AS_S 68   // As row stride (4-way max on transposed writes, f4-aligned reads)

__global__ __launch_bounds__(256)
void pw_gemm(const float* __restrict__ sp, const float* __restrict__ wa,
             const float* __restrict__ ba, float* __restrict__ out)
{
    __shared__ float As[KT * AS_S];   // As[k][co]
    __shared__ float Bs[KT * 256];    // Bs[k][px]

    const int tid  = threadIdx.x;
    const int n    = blockIdx.z;
    const int co0  = blockIdx.y * 64;
    const int px0  = blockIdx.x * 256;
    const int trow = tid >> 5;        // 0..7  -> co sub-block of 8
    const int tcol = tid & 31;        // 0..31 -> px group (two f4 halves)

    const float* spn = sp + (size_t)n * CCH * PLANE + px0;

    float acc[8][8];
    #pragma unroll
    for (int i = 0; i < 8; ++i)
        #pragma unroll
        for (int j = 0; j < 8; ++j) acc[i][j] = 0.f;

    const int arow = tid >> 2;        // 0..63
    const int ac4  = tid & 3;         // 0..3

    for (int k0 = 0; k0 < CCH; k0 += KT) {
        // A tile 64x16 (transpose into As[k][co])
        {
            const float4 v = *reinterpret_cast<const float4*>(
                &wa[(size_t)(co0 + arow) * CCH + k0 + ac4 * 4]);
            As[(ac4 * 4 + 0) * AS_S + arow] = v.x;
            As[(ac4 * 4 + 1) * AS_S + arow] = v.y;
            As[(ac4 * 4 + 2) * AS_S + arow] = v.z;
            As[(ac4 * 4 + 3) * AS_S + arow] = v.w;
        }
        // B tile 16x256, straight float4 copy
        #pragma unroll
        for (int r = 0; r < 4; ++r) {
            const int q  = tid + 256 * r;
            const int br = q >> 6;         // 0..15
            const int bc = q & 63;         // f4 col
            *reinterpret_cast<float4*>(&Bs[br * 256 + bc * 4]) =
                *reinterpret_cast<const float4*>(&spn[(size_t)(k0 + br) * PLANE + bc * 4]);
        }
        __syncthreads();

        #pragma unroll
        for (int kk = 0; kk < KT; ++kk) {
            float a[8], b[8];
            const float4 a0 = *reinterpret_cast<const float4*>(&As[kk * AS_S + trow * 8]);
            const float4 a1 = *reinterpret_cast<const float4*>(&As[kk * AS_S + trow * 8 + 4]);
            a[0]=a0.x; a[1]=a0.y; a[2]=a0.z; a[3]=a0.w;
            a[4]=a1.x; a[5]=a1.y; a[6]=a1.z; a[7]=a1.w;
            const float4 b0v = *reinterpret_cast<const float4*>(&Bs[kk * 256 + tcol * 4]);
            const float4 b1v = *reinterpret_cast<const float4*>(&Bs[kk * 256 + 128 + tcol * 4]);
            b[0]=b0v.x; b[1]=b0v.y; b[2]=b0v.z; b[3]=b0v.w;
            b[4]=b1v.x; b[5]=b1v.y; b[6]=b1v.z; b[7]=b1v.w;
            #pragma unroll
            for (int i = 0; i < 8; ++i)
                #pragma unroll
                for (int j = 0; j < 8; ++j)
                    acc[i][j] = fmaf(a[i], b[j], acc[i][j]);
        }
        __syncthreads();
    }

    // epilogue: + ba, write two f4 halves per co row
    #pragma unroll
    for (int i = 0; i < 8; ++i) {
        const int co  = co0 + trow * 8 + i;
        const float bv = ba[co];
        float* op = out + ((size_t)n * CCH + co) * PLANE + px0;
        *reinterpret_cast<float4*>(op + tcol * 4) =
            make_float4(acc[i][0] + bv, acc[i][1] + bv, acc[i][2] + bv, acc[i][3] + bv);
        *reinterpret_cast<float4*>(op + 128 + tcol * 4) =
            make_float4(acc[i][4] + bv, acc[i][5] + bv, acc[i][6] + bv, acc[i][7] + bv);
    }
}

extern "C" void kernel_launch(void* const* d_in, const int* in_sizes, int n_in,
                              void* d_out, int out_size, void* d_ws, size_t ws_size,
                              hipStream_t stream)
{
    const float* x  = (const float*)d_in[0];
    const float* w0 = (const float*)d_in[1];
    const float* b0 = (const float*)d_in[2];
    const float* w1 = (const float*)d_in[3];
    const float* b1 = (const float*)d_in[4];
    const float* w2 = (const float*)d_in[5];
    const float* b2 = (const float*)d_in[6];
    const float* w3 = (const float*)d_in[7];
    const float* b3 = (const float*)d_in[8];
    const float* w4 = (const float*)d_in[9];
    const float* b4 = (const float*)d_in[10];
    const float* w5 = (const float*)d_in[11];
    const float* b5 = (const float*)d_in[12];
    const float* w6 = (const float*)d_in[13];
    const float* b6 = (const float*)d_in[14];
    const float* wa = (const float*)d_in[15];
    const float* ba = (const float*)d_in[16];
    float* out = (float*)d_out;
    float* sp  = (float*)d_ws;   // spatial intermediate: 16*384*4096 fp32 = 100.7 MB

    dw_fused<<<dim3(NBATCH * CCH), 256, 0, stream>>>(
        x, w0, b0, w1, b1, w2, b2, w3, b3, w4, b4, w5, b5, w6, b6, sp);

    pw_gemm<<<dim3(PLANE / 256, CCH / 64, NBATCH), 256, 0, stream>>>(sp, wa, ba, out);
}

// Round 2
// 155.763 us; speedup vs baseline: 2.3551x; 2.3551x over previous
//
#include <hip/hip_runtime.h>
#include <cstdint>

#define NBATCH 16
#define CCH    384
#define HW     64
#define PLANE  (HW*HW)
#define NTOT   (NBATCH*PLANE)   // 65536 GEMM columns

typedef __attribute__((ext_vector_type(8))) short short8v;
typedef __attribute__((ext_vector_type(4))) float f32x4;

static __device__ __forceinline__ unsigned short f2bf(float f) {
    unsigned int x = __float_as_uint(f);
    unsigned int r = (x + 0x7fffu + ((x >> 16) & 1u)) >> 16;   // RTN-even
    return (unsigned short)r;
}

// ---------------- fused depthwise kernel (unchanged math, bf16 out) ----------------
#define XS_S  68
#define IP_S  92
#define IP_R  84
#define IP_C0 12
#define IP_R0 10

__global__ __launch_bounds__(256)
void dw_fused(const float* __restrict__ x,
              const float* __restrict__ w0, const float* __restrict__ b0,
              const float* __restrict__ w1, const float* __restrict__ b1,
              const float* __restrict__ w2, const float* __restrict__ b2,
              const float* __restrict__ w3, const float* __restrict__ b3,
              const float* __restrict__ w4, const float* __restrict__ b4,
              const float* __restrict__ w5, const float* __restrict__ b5,
              const float* __restrict__ w6, const float* __restrict__ b6,
              unsigned short* __restrict__ spB)
{
    __shared__ float xs[XS_S * XS_S];
    __shared__ float ip[IP_R * IP_S];
    __shared__ float sw0[25];
    __shared__ float swh[21];
    __shared__ float swv[21];
    __shared__ float sb[2];

    const int tid = threadIdx.x;
    const int n   = blockIdx.x / CCH;
    const int c   = blockIdx.x % CCH;

    if (tid < 25) {
        sw0[tid] = w0[c * 25 + tid];
    } else if (tid < 46) {
        const int d = tid - 25, dj = d - 10;
        float v = w5[c * 21 + d];
        if (dj >= -5 && dj <= 5) v += w3[c * 11 + dj + 5];
        if (dj >= -3 && dj <= 3) v += w1[c * 7  + dj + 3];
        swh[d] = v;
    } else if (tid < 67) {
        const int d = tid - 46, di = d - 10;
        float v = w6[c * 21 + d];
        if (di >= -5 && di <= 5) v += w4[c * 11 + di + 5];
        if (di >= -3 && di <= 3) v += w2[c * 7  + di + 3];
        swv[d] = v;
    } else if (tid == 67) {
        sb[0] = b0[c];
    } else if (tid == 68) {
        sb[1] = b1[c] + b2[c] + b3[c] + b4[c] + b5[c] + b6[c];
    }

    {
        float4* p4 = reinterpret_cast<float4*>(ip);
        for (int i = tid; i < (IP_R * IP_S) / 4; i += 256)
            p4[i] = make_float4(0.f, 0.f, 0.f, 0.f);
    }
    {
        const float* xp = x + (size_t)blockIdx.x * PLANE;
        for (int i = tid; i < XS_S * XS_S; i += 256) {
            const int r = i / XS_S, cc = i - r * XS_S;
            const int gh = r - 2, gw = cc - 2;
            float v = 0.f;
            if ((unsigned)gh < (unsigned)HW && (unsigned)gw < (unsigned)HW)
                v = xp[gh * HW + gw];
            xs[i] = v;
        }
    }
    __syncthreads();

    const int h  = tid >> 2;
    const int ws = (tid & 3) << 4;

    float acc[16];
    {
        const float bv = sb[0];
        #pragma unroll
        for (int p = 0; p < 16; ++p) acc[p] = bv;
    }
    #pragma unroll
    for (int i = 0; i < 5; ++i) {
        float f[20];
        const float* row = &xs[(h + i) * XS_S + ws];
        #pragma unroll
        for (int q = 0; q < 5; ++q) {
            const float4 v = *reinterpret_cast<const float4*>(row + 4 * q);
            f[4*q+0] = v.x; f[4*q+1] = v.y; f[4*q+2] = v.z; f[4*q+3] = v.w;
        }
        #pragma unroll
        for (int j = 0; j < 5; ++j) {
            const float wg = sw0[i * 5 + j];
            #pragma unroll
            for (int p = 0; p < 16; ++p) acc[p] += f[p + j] * wg;
        }
    }
    {
        float* dst = &ip[(h + IP_R0) * IP_S + IP_C0 + ws];
        #pragma unroll
        for (int q = 0; q < 4; ++q)
            *reinterpret_cast<float4*>(dst + 4 * q) =
                make_float4(acc[4*q], acc[4*q+1], acc[4*q+2], acc[4*q+3]);
    }
    __syncthreads();

    {
        const float bv = sb[1];
        #pragma unroll
        for (int p = 0; p < 16; ++p) acc[p] = bv;
    }
    {
        float f[40];
        const float* row = &ip[(h + IP_R0) * IP_S + ws];
        #pragma unroll
        for (int q = 0; q < 10; ++q) {
            const float4 v = *reinterpret_cast<const float4*>(row + 4 * q);
            f[4*q+0] = v.x; f[4*q+1] = v.y; f[4*q+2] = v.z; f[4*q+3] = v.w;
        }
        #pragma unroll
        for (int j = 0; j < 21; ++j) {
            const float wg = swh[j];
            #pragma unroll
            for (int p = 0; p < 16; ++p) acc[p] += f[2 + p + j] * wg;
        }
    }
    #pragma unroll
    for (int i = 0; i < 21; ++i) {
        const float wg = swv[i];
        const float* row = &ip[(h + i) * IP_S + IP_C0 + ws];
        #pragma unroll
        for (int q = 0; q < 4; ++q) {
            const float4 v = *reinterpret_cast<const float4*>(row + 4 * q);
            acc[4*q+0] += v.x * wg; acc[4*q+1] += v.y * wg;
            acc[4*q+2] += v.z * wg; acc[4*q+3] += v.w * wg;
        }
    }
    // store spatial as bf16 in [c][(n,px)] layout  (GEMM B-matrix row = channel)
    {
        unsigned short u[16];
        #pragma unroll
        for (int p = 0; p < 16; ++p) u[p] = f2bf(acc[p]);
        unsigned short* op = spB + ((size_t)c * NBATCH + n) * PLANE + h * HW + ws;
        *reinterpret_cast<short8v*>(op)     = *reinterpret_cast<short8v*>(&u[0]);
        *reinterpret_cast<short8v*>(op + 8) = *reinterpret_cast<short8v*>(&u[8]);
    }
}

// ---------------- wa fp32 -> bf16 ----------------
__global__ __launch_bounds__(256)
void wa_cvt(const float* __restrict__ wa, unsigned short* __restrict__ waB)
{
    const int i = blockIdx.x * 256 + threadIdx.x;   // 36864 float4s
    const float4 v = reinterpret_cast<const float4*>(wa)[i];
    ushort4 o;
    o.x = f2bf(v.x); o.y = f2bf(v.y); o.z = f2bf(v.z); o.w = f2bf(v.w);
    reinterpret_cast<ushort4*>(waB)[i] = o;
}

// ---------------- 1x1 conv as bf16 MFMA GEMM ----------------
// C(384 x 65536) = waB(384x384) @ spB(384x65536); out[n][co][px], col=(n,px)
// block: BM=128 x BN=128, BK=64, 256 thr = 4 waves (2x2), wave = 64x64 (4x4 frags)
__global__ __launch_bounds__(256)
void pw_mfma(const unsigned short* __restrict__ spB,
             const unsigned short* __restrict__ waB,
             const float* __restrict__ ba, float* __restrict__ out)
{
    __shared__ unsigned short As[128 * 64];   // [row][k], row stride 128 B, XOR-swz (row&7)<<4
    __shared__ unsigned short Bs[128 * 64];   // [col][k], row stride 128 B, XOR-swz s(col)<<4

    const int tid  = threadIdx.x;
    const int lane = tid & 63;
    const int wid  = tid >> 6;
    const int wrow = wid >> 1;           // 0..1
    const int wcol = wid & 1;            // 0..1

    const int mtile = blockIdx.y;        // 0..2
    const int ntile = blockIdx.x;        // 0..511
    const int co0   = mtile * 128;
    const int col0  = ntile * 128;

    f32x4 acc[4][4];
    #pragma unroll
    for (int m = 0; m < 4; ++m)
        #pragma unroll
        for (int nn = 0; nn < 4; ++nn) acc[m][nn] = (f32x4){0.f, 0.f, 0.f, 0.f};

    // A-staging constants (linear LDS dest, pre-swizzled global source)
    // L = (wid*4+q)*1024 + lane*16 ; row = L>>7 ; kbyte = (L&127) ^ ((row&7)<<4)
    const char* waBb = (const char*)waB;

    for (int kt = 0; kt < 6; ++kt) {
        // ---- stage A (128x64 bf16 = 16 KB) via global_load_lds x16 ----
        #pragma unroll
        for (int q = 0; q < 4; ++q) {
            const int L     = (wid * 4 + q) * 1024 + lane * 16;
            const int row   = L >> 7;
            const int kbyte = (L & 127) ^ ((row & 7) << 4);
            const void* src = (const void*)(waBb + (size_t)(co0 + row) * 768 + kt * 128 + kbyte);
            __builtin_amdgcn_global_load_lds(
                (const __attribute__((address_space(1))) void*)src,
                (__attribute__((address_space(3))) void*)((char*)As + (wid * 4 + q) * 1024),
                16, 0, 0);
        }

        // ---- stage B (64k x 128col) transposed into Bs[col][k] ----
        #pragma unroll
        for (int j = 0; j < 2; ++j) {
            const int kloc  = j * 32 + 2 * (tid >> 4);          // even, 0..62
            const int cbase = 8 * (tid & 15);                    // 0..120
            const unsigned int* gp =
                (const unsigned int*)(spB + (size_t)(kt * 64 + kloc) * NTOT + col0 + cbase);
            unsigned int g0[4], g1[4];
            *(uint4*)g0 = *(const uint4*)gp;
            *(uint4*)g1 = *(const uint4*)(gp + NTOT / 2);        // next k row
            #pragma unroll
            for (int r = 0; r < 8; ++r) {
                const unsigned int w0 = g0[r >> 1], w1 = g1[r >> 1];
                const unsigned int lo = (r & 1) ? (w0 >> 16) : (w0 & 0xffffu);
                const unsigned int hi = (r & 1) ? (w1 >> 16) : (w1 & 0xffffu);
                const unsigned int val = lo | (hi << 16);
                const int colL = cbase + r;
                const int s    = (r ^ (tid & 7)) & 7;            // (colL&7)^((colL>>3)&7)
                const int byte = colL * 128 + ((kloc * 2) ^ (s << 4));
                *(unsigned int*)((char*)Bs + byte) = val;
            }
        }
        __syncthreads();

        // ---- compute: 2 k-steps x 4x4 fragments ----
        #pragma unroll
        for (int kk = 0; kk < 2; ++kk) {
            short8v aF[4], bF[4];
            const int kbyte = kk * 64 + (lane >> 4) * 16;
            #pragma unroll
            for (int m = 0; m < 4; ++m) {
                const int row = wrow * 64 + m * 16 + (lane & 15);
                aF[m] = *(const short8v*)((const char*)As + row * 128 + (kbyte ^ ((row & 7) << 4)));
            }
            #pragma unroll
            for (int nn = 0; nn < 4; ++nn) {
                const int col = wcol * 64 + nn * 16 + (lane & 15);
                const int s   = ((col & 7) ^ ((col >> 3) & 7)) << 4;
                bF[nn] = *(const short8v*)((const char*)Bs + col * 128 + (kbyte ^ s));
            }
            #pragma unroll
            for (int m = 0; m < 4; ++m)
                #pragma unroll
                for (int nn = 0; nn < 4; ++nn)
                    acc[m][nn] = __builtin_amdgcn_mfma_f32_16x16x32_bf16(
                        aF[m], bF[nn], acc[m][nn], 0, 0, 0);
        }
        __syncthreads();
    }

    // ---- epilogue: +ba, store fp32 ----
    const int nb  = (col0) >> 12;          // batch (BN=128 never crosses 4096)
    const int px0 = (col0) & 4095;
    #pragma unroll
    for (int m = 0; m < 4; ++m) {
        #pragma unroll
        for (int r = 0; r < 4; ++r) {
            const int co = co0 + wrow * 64 + m * 16 + 4 * (lane >> 4) + r;
            const float bv = ba[co];
            float* orow = out + ((size_t)(nb * CCH + co)) * PLANE + px0 + wcol * 64 + (lane & 15);
            #pragma unroll
            for (int nn = 0; nn < 4; ++nn)
                orow[nn * 16] = acc[m][nn][r] + bv;
        }
    }
}

extern "C" void kernel_launch(void* const* d_in, const int* in_sizes, int n_in,
                              void* d_out, int out_size, void* d_ws, size_t ws_size,
                              hipStream_t stream)
{
    const float* x  = (const float*)d_in[0];
    const float* w0 = (const float*)d_in[1];
    const float* b0 = (const float*)d_in[2];
    const float* w1 = (const float*)d_in[3];
    const float* b1 = (const float*)d_in[4];
    const float* w2 = (const float*)d_in[5];
    const float* b2 = (const float*)d_in[6];
    const float* w3 = (const float*)d_in[7];
    const float* b3 = (const float*)d_in[8];
    const float* w4 = (const float*)d_in[9];
    const float* b4 = (const float*)d_in[10];
    const float* w5 = (const float*)d_in[11];
    const float* b5 = (const float*)d_in[12];
    const float* w6 = (const float*)d_in[13];
    const float* b6 = (const float*)d_in[14];
    const float* wa = (const float*)d_in[15];
    const float* ba = (const float*)d_in[16];
    float* out = (float*)d_out;

    unsigned short* spB = (unsigned short*)d_ws;                       // 50,331,648 B
    unsigned short* waB = (unsigned short*)((char*)d_ws + 50331648);   // 294,912 B

    wa_cvt<<<dim3(36864 / 256), 256, 0, stream>>>(wa, waB);
    dw_fused<<<dim3(NBATCH * CCH), 256, 0, stream>>>(
        x, w0, b0, w1, b1, w2, b2, w3, b3, w4, b4, w5, b5, w6, b6, spB);
    pw_mfma<<<dim3(NTOT / 128, CCH / 128), 256, 0, stream>>>(spB, waB, ba, out);
}